// Round 10
// baseline (242.192 us; speedup 1.0000x reference)
//
#include <hip/hip_runtime.h>

// LIF recurrence over T, parallel over (B,H). x,out: (B,T,H) fp32.
// B=64, T=1000, H=512. 512 blocks x 64 threads = 1 wave/block, 2 waves/CU.
//
// Input pipeline: LDS-DMA (global_load_lds) + hand-counted vmcnt, 4 buffers,
// prefetch distance 3. vmcnt model (matches LLVM SIInsertWaitcnts): single
// in-order queue of loads AND stores; VWAIT(N) with N = #ops issued after
// the op of interest guarantees it retired. Round-9 lesson: stores must be
// COUNTED IN the budget, or every wait forces a full store drain.
// Per chunk: 10 DMA loads + 10 dwordx4 stores = 20 vmcnt entries;
// steady-state younger set = 3x20 = 60 <= 63 cap.
//
// Output path: spikes -> LDS staging tile (ds_write_b32) -> ds_read_b128
// -> 10 global_store_dwordx4 (coalesced, 4 rows per op), mirroring the
// input staging layout: lane i <-> row (i>>4), cols (i&15)*4..+3, because
// LDS byte 16*i == row-linear float 4*i.

#define LIF_T 1000
#define LIF_H 512
#define U 40          // timesteps per chunk; 25 chunks
#define NB 4          // input LDS buffers; prefetch distance 3

#define AS1 __attribute__((address_space(1)))
#define AS3 __attribute__((address_space(3)))

typedef float f4 __attribute__((ext_vector_type(4)));

__global__ __launch_bounds__(64, 1) void lif_kernel(
    const float* __restrict__ x,
    const float* __restrict__ decay,
    const float* __restrict__ thr_p,
    float* __restrict__ out)
{
    __shared__ float lds_in[NB][U][64];   // 40960 B
    __shared__ float lds_out[U][64];      // 10240 B

    const int lane = threadIdx.x;          // 0..63
    const int blk  = blockIdx.x;           // 0..511
    const int b    = blk >> 3;             // batch
    const int h0   = (blk & 7) << 6;       // column base (multiple of 64)

    // clamp(0.5, v, 1.0)
    const float alpha = fminf(fmaxf(decay[0], 0.5f), 1.0f);
    const float beta  = fminf(fmaxf(decay[1], 0.5f), 1.0f);
    // match XLA's separate-op rounding; no fma contraction anywhere
    const float oma = __fsub_rn(1.0f, alpha);
    const float omb = __fsub_rn(1.0f, beta);
    const float thr = thr_p[0];

    // per-lane global source for staging (row lane>>4, 16B slice lane&15)
    const float* gsrc = x + ((size_t)b * LIF_T + (lane >> 4)) * LIF_H
                          + h0 + (lane & 15) * 4;
    // per-lane global dest, same geometry (dwordx4 stores)
    float* sbase = out + ((size_t)b * LIF_T + (lane >> 4)) * LIF_H
                       + h0 + (lane & 15) * 4;

    // LDS byte addresses
    const unsigned inbase  = (unsigned)(size_t)(const AS3 void*)&lds_in[0][0][0]
                           + (unsigned)lane * 4u;
    const unsigned outwb   = (unsigned)(size_t)(const AS3 void*)&lds_out[0][0]
                           + (unsigned)lane * 4u;
    const unsigned outrb   = (unsigned)(size_t)(const AS3 void*)&lds_out[0][0]
                           + (unsigned)lane * 16u;

    float mem = 0.f, syn = 0.f, spike = 0.f;

// stage chunk c into input buffer buf: 10 width-16 LDS-DMA ops (4 rows each)
#define ISSUE(c, buf) do {                                                  \
    _Pragma("unroll")                                                       \
    for (int g = 0; g < U / 4; ++g)                                         \
        __builtin_amdgcn_global_load_lds(                                   \
            (AS1 void*)(gsrc + (size_t)((c) * U + g * 4) * LIF_H),          \
            (AS3 void*)&lds_in[buf][g * 4][0], 16, 0, 0);                   \
} while (0)

// counted vmcnt wait + scheduling fence (rule 18)
#define VWAIT(nn) do {                                                      \
    asm volatile("s_waitcnt vmcnt(" #nn ")" ::: "memory");                  \
    __builtin_amdgcn_sched_barrier(0); } while (0)

#define LGKM0 do {                                                          \
    asm volatile("s_waitcnt lgkmcnt(0)" ::: "memory");                      \
    __builtin_amdgcn_sched_barrier(0); } while (0)

// consume chunk c from buffer buf; emits 10 dwordx4 stores (vmcnt entries)
#define COMPUTE(c, buf) do {                                                \
    float xv[U];                                                            \
    _Pragma("unroll")                                                       \
    for (int u = 0; u < U; ++u)                                             \
        asm volatile("ds_read_b32 %0, %1" : "=v"(xv[u])                     \
            : "v"(inbase + (unsigned)((buf) * (U * 256) + u * 256)));       \
    LGKM0;                                                                  \
    _Pragma("unroll")                                                       \
    for (int u = 0; u < U; ++u) {                                           \
        const float r_ = __fmul_rn(mem, spike);                             \
        mem = __fsub_rn(mem, r_);                                           \
        mem = __fadd_rn(__fmul_rn(alpha, mem), __fmul_rn(oma, syn));        \
        syn = __fadd_rn(__fmul_rn(beta, syn), __fmul_rn(omb, xv[u]));       \
        spike = (__fsub_rn(mem, thr) >= 0.0f) ? 1.0f : 0.0f;                \
        asm volatile("ds_write_b32 %0, %1"                                  \
            :: "v"(outwb + (unsigned)(u * 256)), "v"(spike));               \
    }                                                                       \
    LGKM0;                                                                  \
    f4 v4[U / 4];                                                           \
    _Pragma("unroll")                                                       \
    for (int g = 0; g < U / 4; ++g)                                         \
        asm volatile("ds_read_b128 %0, %1" : "=v"(v4[g])                    \
            : "v"(outrb + (unsigned)(g * 1024)));                           \
    LGKM0;                                                                  \
    _Pragma("unroll")                                                       \
    for (int g = 0; g < U / 4; ++g)                                         \
        __builtin_nontemporal_store(v4[g],                                  \
            (f4*)(sbase + (size_t)((c) * U + g * 4) * LIF_H));              \
} while (0)

    // prologue: fill all 4 input buffers (40 DMA loads)
    ISSUE(0, 0); ISSUE(1, 1); ISSUE(2, 2); ISSUE(3, 3);

    // younger-op counts (loads+stores, in-order queue):
    VWAIT(30); COMPUTE(0, 0); ISSUE(4, 0);   // L1,L2,L3
    VWAIT(40); COMPUTE(1, 1); ISSUE(5, 1);   // L2,L3,S0,L4
    VWAIT(50); COMPUTE(2, 2); ISSUE(6, 2);   // L3,S0,L4,S1,L5
    // steady state: younger = S(c-3),L(c+1),S(c-2),L(c+2),S(c-1),L(c+3) = 60
    #pragma unroll 1
    for (int c = 3; c <= 15; c += 4) {
        VWAIT(60); COMPUTE(c + 0, 3); ISSUE(c + 4, 3);
        VWAIT(60); COMPUTE(c + 1, 0); ISSUE(c + 5, 0);
        VWAIT(60); COMPUTE(c + 2, 1); ISSUE(c + 6, 1);
        VWAIT(60); COMPUTE(c + 3, 2); ISSUE(c + 7, 2);
    }
    // computed 0..18, issued 0..22
    VWAIT(60); COMPUTE(19, 3); ISSUE(23, 3);
    VWAIT(60); COMPUTE(20, 0); ISSUE(24, 0);
    VWAIT(60); COMPUTE(21, 1);               // S18,L22,S19,L23,S20,L24
    VWAIT(50); COMPUTE(22, 2);               // S19,L23,S20,L24,S21
    VWAIT(40); COMPUTE(23, 3);               // S20,L24,S21,S22
    VWAIT(30); COMPUTE(24, 0);               // S21,S22,S23

#undef ISSUE
#undef VWAIT
#undef LGKM0
#undef COMPUTE
}

extern "C" void kernel_launch(void* const* d_in, const int* in_sizes, int n_in,
                              void* d_out, int out_size, void* d_ws, size_t ws_size,
                              hipStream_t stream) {
    const float* x     = (const float*)d_in[0];
    const float* decay = (const float*)d_in[1];
    const float* thr   = (const float*)d_in[2];
    float* out = (float*)d_out;

    const int grid = 512;   // 64 batches x 8 column-groups
    lif_kernel<<<grid, 64, 0, stream>>>(x, decay, thr, out);
}

// Round 12
// 240.673 us; speedup vs baseline: 1.0063x; 1.0063x over previous
//
#include <hip/hip_runtime.h>

// LIF recurrence over T, parallel over (B,H). x,out: (B,T,H) fp32.
// B=64, T=1000, H=512. 512 blocks x 64 threads = 1 wave/block, 2 waves/CU.
//
// Input pipeline: LDS-DMA (global_load_lds) + hand-counted vmcnt, 4 buffers,
// prefetch distance 3. vmcnt decrements IN ORDER, so VWAIT(N) with
// N <= #ops issued after the op of interest guarantees it retired (extra
// younger ops only make the wait stricter).
// Per chunk: 10 DMA loads + 10 dwordx4 stores = 20 vmcnt entries;
// steady-state younger set = 3x20 = 60 <= 63 cap.
//
// Round-10 lesson candidate: NONTEMPORAL stores ack from HBM (bypass L2);
// in-order vmcnt decrement makes 4-period-old store acks gate every load
// retirement -> ~2.7us stall per chunk. This round: plain f4 stores
// (ack from L2/L3), everything else identical to round 10.
//
// Output path: spikes -> LDS staging tile (ds_write_b32) -> ds_read_b128
// -> 10 global_store_dwordx4 (coalesced, 4 rows per op), mirroring the
// input staging layout: lane i <-> row (i>>4), cols (i&15)*4..+3, because
// LDS byte 16*i == row-linear float 4*i.

#define LIF_T 1000
#define LIF_H 512
#define U 40          // timesteps per chunk; 25 chunks
#define NB 4          // input LDS buffers; prefetch distance 3

#define AS1 __attribute__((address_space(1)))
#define AS3 __attribute__((address_space(3)))

typedef float f4 __attribute__((ext_vector_type(4)));

__global__ __launch_bounds__(64, 1) void lif_kernel(
    const float* __restrict__ x,
    const float* __restrict__ decay,
    const float* __restrict__ thr_p,
    float* __restrict__ out)
{
    __shared__ float lds_in[NB][U][64];   // 40960 B
    __shared__ float lds_out[U][64];      // 10240 B

    const int lane = threadIdx.x;          // 0..63
    const int blk  = blockIdx.x;           // 0..511
    const int b    = blk >> 3;             // batch
    const int h0   = (blk & 7) << 6;       // column base (multiple of 64)

    // clamp(0.5, v, 1.0)
    const float alpha = fminf(fmaxf(decay[0], 0.5f), 1.0f);
    const float beta  = fminf(fmaxf(decay[1], 0.5f), 1.0f);
    // match XLA's separate-op rounding; no fma contraction anywhere
    const float oma = __fsub_rn(1.0f, alpha);
    const float omb = __fsub_rn(1.0f, beta);
    const float thr = thr_p[0];

    // per-lane global source for staging (row lane>>4, 16B slice lane&15)
    const float* gsrc = x + ((size_t)b * LIF_T + (lane >> 4)) * LIF_H
                          + h0 + (lane & 15) * 4;
    // per-lane global dest, same geometry (dwordx4 stores)
    float* sbase = out + ((size_t)b * LIF_T + (lane >> 4)) * LIF_H
                       + h0 + (lane & 15) * 4;

    // LDS byte addresses
    const unsigned inbase  = (unsigned)(size_t)(const AS3 void*)&lds_in[0][0][0]
                           + (unsigned)lane * 4u;
    const unsigned outwb   = (unsigned)(size_t)(const AS3 void*)&lds_out[0][0]
                           + (unsigned)lane * 4u;
    const unsigned outrb   = (unsigned)(size_t)(const AS3 void*)&lds_out[0][0]
                           + (unsigned)lane * 16u;

    float mem = 0.f, syn = 0.f, spike = 0.f;

// stage chunk c into input buffer buf: 10 width-16 LDS-DMA ops (4 rows each)
#define ISSUE(c, buf) do {                                                  \
    _Pragma("unroll")                                                       \
    for (int g = 0; g < U / 4; ++g)                                         \
        __builtin_amdgcn_global_load_lds(                                   \
            (AS1 void*)(gsrc + (size_t)((c) * U + g * 4) * LIF_H),          \
            (AS3 void*)&lds_in[buf][g * 4][0], 16, 0, 0);                   \
} while (0)

// counted vmcnt wait + scheduling fence (rule 18)
#define VWAIT(nn) do {                                                      \
    asm volatile("s_waitcnt vmcnt(" #nn ")" ::: "memory");                  \
    __builtin_amdgcn_sched_barrier(0); } while (0)

#define LGKM0 do {                                                          \
    asm volatile("s_waitcnt lgkmcnt(0)" ::: "memory");                      \
    __builtin_amdgcn_sched_barrier(0); } while (0)

// consume chunk c from buffer buf; emits 10 dwordx4 stores (vmcnt entries)
#define COMPUTE(c, buf) do {                                                \
    float xv[U];                                                            \
    _Pragma("unroll")                                                       \
    for (int u = 0; u < U; ++u)                                             \
        asm volatile("ds_read_b32 %0, %1" : "=v"(xv[u])                     \
            : "v"(inbase + (unsigned)((buf) * (U * 256) + u * 256)));       \
    LGKM0;                                                                  \
    _Pragma("unroll")                                                       \
    for (int u = 0; u < U; ++u) {                                           \
        const float r_ = __fmul_rn(mem, spike);                             \
        mem = __fsub_rn(mem, r_);                                           \
        mem = __fadd_rn(__fmul_rn(alpha, mem), __fmul_rn(oma, syn));        \
        syn = __fadd_rn(__fmul_rn(beta, syn), __fmul_rn(omb, xv[u]));       \
        spike = (__fsub_rn(mem, thr) >= 0.0f) ? 1.0f : 0.0f;                \
        asm volatile("ds_write_b32 %0, %1"                                  \
            :: "v"(outwb + (unsigned)(u * 256)), "v"(spike));               \
    }                                                                       \
    LGKM0;                                                                  \
    f4 v4[U / 4];                                                           \
    _Pragma("unroll")                                                       \
    for (int g = 0; g < U / 4; ++g)                                         \
        asm volatile("ds_read_b128 %0, %1" : "=v"(v4[g])                    \
            : "v"(outrb + (unsigned)(g * 1024)));                           \
    LGKM0;                                                                  \
    _Pragma("unroll")                                                       \
    for (int g = 0; g < U / 4; ++g)                                         \
        *(f4*)(sbase + (size_t)((c) * U + g * 4) * LIF_H) = v4[g];          \
    __builtin_amdgcn_sched_barrier(0);                                      \
} while (0)

    // prologue: fill all 4 input buffers (40 DMA loads)
    ISSUE(0, 0); ISSUE(1, 1); ISSUE(2, 2); ISSUE(3, 3);

    // younger-op counts (loads+stores, in-order queue):
    VWAIT(30); COMPUTE(0, 0); ISSUE(4, 0);   // L1,L2,L3
    VWAIT(40); COMPUTE(1, 1); ISSUE(5, 1);   // L2,L3,S0,L4
    VWAIT(50); COMPUTE(2, 2); ISSUE(6, 2);   // L3,S0,L4,S1,L5
    // steady state: younger = S(c-3),L(c+1),S(c-2),L(c+2),S(c-1),L(c+3) = 60
    #pragma unroll 1
    for (int c = 3; c <= 15; c += 4) {
        VWAIT(60); COMPUTE(c + 0, 3); ISSUE(c + 4, 3);
        VWAIT(60); COMPUTE(c + 1, 0); ISSUE(c + 5, 0);
        VWAIT(60); COMPUTE(c + 2, 1); ISSUE(c + 6, 1);
        VWAIT(60); COMPUTE(c + 3, 2); ISSUE(c + 7, 2);
    }
    // computed 0..18, issued 0..22
    VWAIT(60); COMPUTE(19, 3); ISSUE(23, 3);
    VWAIT(60); COMPUTE(20, 0); ISSUE(24, 0);
    VWAIT(60); COMPUTE(21, 1);               // S18,L22,S19,L23,S20,L24
    VWAIT(50); COMPUTE(22, 2);               // S19,L23,S20,L24,S21
    VWAIT(40); COMPUTE(23, 3);               // S20,L24,S21,S22
    VWAIT(30); COMPUTE(24, 0);               // S21,S22,S23

#undef ISSUE
#undef VWAIT
#undef LGKM0
#undef COMPUTE
}

extern "C" void kernel_launch(void* const* d_in, const int* in_sizes, int n_in,
                              void* d_out, int out_size, void* d_ws, size_t ws_size,
                              hipStream_t stream) {
    const float* x     = (const float*)d_in[0];
    const float* decay = (const float*)d_in[1];
    const float* thr   = (const float*)d_in[2];
    float* out = (float*)d_out;

    const int grid = 512;   // 64 batches x 8 column-groups
    lif_kernel<<<grid, 64, 0, stream>>>(x, decay, thr, out);
}